// Round 6
// baseline (256.394 us; speedup 1.0000x reference)
//
#include <hip/hip_runtime.h>

#define K_CODES 1024
#define D_DIM 128
#define N_ROWS 65536
#define DECAY_F 0.99f
#define OMD_F 0.01f
#define EPS_F 1e-5f

#define EPAD 136                       // padded bf16 row (272 B)
#define CHUNK_CODES 128
#define CHUNK_USHORT (2 * CHUNK_CODES * EPAD)   // 34816 ushorts = 69632 B
#define NT 4                           // row tiles per wave (64 rows/wave)
#define HALF_CODES 512                 // codes per block (K-split)
#define HALF_CHUNKS 4
#define SEG_TILE 64

// ---------------------------------------------------------------------------
// ws layout (float units). [0, WS_ZERO_END) zeroed by vq_prep every call.
// ---------------------------------------------------------------------------
#define WS_CNT     0
#define WS_LOSS    1024
#define WS_BE      1028
#define WS_ZERO_END (1028 + 131072)    // 132100
#define WS_ENORM   132100
#define WS_SMOOTH  133124
#define WS_CUR     134148
#define WS_FIDX    135172
#define WS_BUCKET  200708
#define WS_SCODE   266244
#define WS_CAND    331780              // u32[65536][4]
#define WS_EIMG    593924              // ushort[8][2][128][136]

typedef __bf16 bf8_t __attribute__((ext_vector_type(8)));
typedef float  f4_t  __attribute__((ext_vector_type(4)));

__device__ inline unsigned short f2bf_bits(float f) {
    __bf16 h = (__bf16)f;
    return __builtin_bit_cast(unsigned short, h);
}
__device__ inline float bf_bits2f(unsigned short u) {
    __bf16 h = __builtin_bit_cast(__bf16, u);
    return (float)h;
}

// async global->LDS, 16 B per lane (HW: lds base is wave-uniform + lane*16)
__device__ inline void gld16(const void* g, void* l) {
    __builtin_amdgcn_global_load_lds(
        (const __attribute__((address_space(1))) void*)g,
        (__attribute__((address_space(3))) void*)l, 16, 0, 0);
}

// ---------------------------------------------------------------------------
// Prep: zero cnt/loss/be + enorm + bf16 hi/lo split image. grid 128 x 256.
// ---------------------------------------------------------------------------
__global__ void vq_prep(const float* __restrict__ emb, float* __restrict__ ws,
                        float* __restrict__ enorm, unsigned short* __restrict__ eimg) {
    int t = blockIdx.x * blockDim.x + threadIdx.x;   // 32768
    for (int i = t; i < WS_ZERO_END; i += 32768) ws[i] = 0.f;

    int code = t >> 5;
    int q = t & 31;
    float4 v = ((const float4*)(emb + (size_t)code * D_DIM))[q];
    int chunk = code >> 7, c = code & 127;
    size_t hbase = (size_t)chunk * CHUNK_USHORT + (size_t)c * EPAD + q * 4;
    size_t lbase = hbase + (size_t)CHUNK_CODES * EPAD;
    float vv[4] = {v.x, v.y, v.z, v.w};
    ushort4 hi, lo;
    unsigned short* hp = (unsigned short*)&hi;
    unsigned short* lp = (unsigned short*)&lo;
#pragma unroll
    for (int i = 0; i < 4; ++i) {
        unsigned short hb = f2bf_bits(vv[i]);
        hp[i] = hb;
        lp[i] = f2bf_bits(vv[i] - bf_bits2f(hb));
    }
    *(ushort4*)(eimg + hbase) = hi;
    *(ushort4*)(eimg + lbase) = lo;

    float s = v.x * v.x + v.y * v.y + v.z * v.z + v.w * v.w;
#pragma unroll
    for (int o = 1; o < 32; o <<= 1) s += __shfl_xor(s, o, 64);
    if (q == 0) enorm[code] = s;
}

// ---------------------------------------------------------------------------
__device__ inline void top2_update(float s, int code, float& s1, int& i1, float& s2, int& i2) {
    bool b1 = s < s1;
    bool b2 = s < s2;
    s2 = b1 ? s1 : (b2 ? s : s2);
    i2 = b1 ? i1 : (b2 ? code : i2);
    s1 = b1 ? s : s1;
    i1 = b1 ? code : i1;
}

__device__ inline void top2_merge(float& s1, int& i1, float& s2, int& i2,
                                  float t1, int j1, float t2, int j2) {
    bool bf = (t1 < s1) || (t1 == s1 && j1 < i1);
    float ns1 = bf ? t1 : s1;  int ni1 = bf ? j1 : i1;
    float ca  = bf ? s1 : t1;  int ia  = bf ? i1 : j1;
    float cb  = bf ? t2 : s2;  int ib  = bf ? j2 : i2;
    bool bs = (ca < cb) || (ca == cb && ia < ib);
    s1 = ns1; i1 = ni1;
    s2 = bs ? ca : cb; i2 = bs ? ia : ib;
}

// ---------------------------------------------------------------------------
// Score (K-split): block = (row_group, half). 256 thr = 4 waves, NT=4
// -> 256 rows x 512 codes per block. Grid 512 -> 2048 waves, 8 waves/CU.
// LDS: single chunk buffer 68 KB + en 2 KB -> 2 blocks/CU.
// Emits top-2 per (row, half) -> cand[row][half*2 + {0,1}].
// ---------------------------------------------------------------------------
__global__ __launch_bounds__(256, 2) void vq_score(
    const float* __restrict__ z, const unsigned short* __restrict__ eimg,
    const float* __restrict__ enorm_g, unsigned int* __restrict__ cand)
{
    __shared__ __align__(16) unsigned short lds[CHUNK_USHORT];   // 69632 B
    __shared__ __align__(16) float lds_en[HALF_CODES];           // 2 KB

    const int tid  = threadIdx.x;
    const int wv   = tid >> 6;
    const int lane = tid & 63;
    const int l16  = lane & 15;
    const int quad = lane >> 4;
    const int half = blockIdx.x & 1;
    const int rg   = blockIdx.x >> 1;
    const int rowbase = rg * 256 + wv * 64;

    if (tid < HALF_CODES / 4)
        ((float4*)lds_en)[tid] = ((const float4*)(enorm_g + half * HALF_CODES))[tid];

    // stage chunk 0 of this half
    {
        const char* gs = (const char*)(eimg + (size_t)(half * HALF_CHUNKS) * CHUNK_USHORT);
        char* ls = (char*)lds;
        int wb = wv * 17408;
#pragma unroll
        for (int i = 0; i < 17; ++i)
            gld16(gs + wb + i * 1024 + lane * 16, ls + wb + i * 1024);
    }

    // resident z fragments (bf16 hi/lo)
    bf8_t zh[NT][4], zl[NT][4];
#pragma unroll
    for (int nt = 0; nt < NT; ++nt) {
        int row = rowbase + nt * 16 + l16;
        const float* zr = z + (size_t)row * D_DIM;
#pragma unroll
        for (int ks = 0; ks < 4; ++ks) {
            const float4* p = (const float4*)(zr + ks * 32 + quad * 8);
            float4 a = p[0], b = p[1];
            float v[8] = {a.x, a.y, a.z, a.w, b.x, b.y, b.z, b.w};
#pragma unroll
            for (int i = 0; i < 8; ++i) {
                __bf16 hh = (__bf16)v[i];
                zh[nt][ks][i] = hh;
                zl[nt][ks][i] = (__bf16)(v[i] - (float)hh);
            }
        }
    }

    float s1[NT], s2[NT];
    int   i1[NT], i2[NT];
#pragma unroll
    for (int nt = 0; nt < NT; ++nt) { s1[nt] = 3.4e38f; s2[nt] = 3.4e38f; i1[nt] = 0; i2[nt] = 0; }

    __syncthreads();   // chunk-0 staging drained

    for (int c = 0; c < HALF_CHUNKS; ++c) {
#pragma unroll
        for (int cg = 0; cg < 4; ++cg) {     // 32 codes per pass
            f4_t acc[2][NT];
#pragma unroll
            for (int ct = 0; ct < 2; ++ct)
#pragma unroll
                for (int nt = 0; nt < NT; ++nt) acc[ct][nt] = (f4_t)(0.f);

#pragma unroll
            for (int ks = 0; ks < 4; ++ks) {
                bf8_t ah[2], al[2];
#pragma unroll
                for (int ct = 0; ct < 2; ++ct) {
                    int cl = cg * 32 + ct * 16 + l16;
                    int base = cl * EPAD + ks * 32 + quad * 8;
                    ah[ct] = *(const bf8_t*)&lds[base];
                    al[ct] = *(const bf8_t*)&lds[CHUNK_CODES * EPAD + base];
                }
#pragma unroll
                for (int ct = 0; ct < 2; ++ct)
#pragma unroll
                    for (int nt = 0; nt < NT; ++nt) {
                        acc[ct][nt] = __builtin_amdgcn_mfma_f32_16x16x32_bf16(
                            ah[ct], zh[nt][ks], acc[ct][nt], 0, 0, 0);
                        acc[ct][nt] = __builtin_amdgcn_mfma_f32_16x16x32_bf16(
                            al[ct], zh[nt][ks], acc[ct][nt], 0, 0, 0);
                        acc[ct][nt] = __builtin_amdgcn_mfma_f32_16x16x32_bf16(
                            ah[ct], zl[nt][ks], acc[ct][nt], 0, 0, 0);
                    }
            }

#pragma unroll
            for (int ct = 0; ct < 2; ++ct) {
                int lc = c * 128 + cg * 32 + ct * 16 + quad * 4;   // local code base
                float4 en4 = *(const float4*)&lds_en[lc];
                float env[4] = {en4.x, en4.y, en4.z, en4.w};
                int gc = half * HALF_CODES + lc;
#pragma unroll
                for (int nt = 0; nt < NT; ++nt)
#pragma unroll
                    for (int r = 0; r < 4; ++r) {
                        float s = env[r] - 2.0f * acc[ct][nt][r];
                        top2_update(s, gc + r, s1[nt], i1[nt], s2[nt], i2[nt]);
                    }
            }
        }
        __syncthreads();   // everyone done reading this chunk
        if (c + 1 < HALF_CHUNKS) {
            const char* gs = (const char*)(eimg +
                (size_t)(half * HALF_CHUNKS + c + 1) * CHUNK_USHORT);
            char* ls = (char*)lds;
            int wb = wv * 17408;
#pragma unroll
            for (int i = 0; i < 17; ++i)
                gld16(gs + wb + i * 1024 + lane * 16, ls + wb + i * 1024);
            __syncthreads();   // staging drained
        }
    }

    // cross-quad merge (quads saw disjoint codes)
#pragma unroll
    for (int off = 16; off <= 32; off <<= 1) {
#pragma unroll
        for (int nt = 0; nt < NT; ++nt) {
            float t1 = __shfl_xor(s1[nt], off, 64);
            int   j1 = __shfl_xor(i1[nt], off, 64);
            float t2 = __shfl_xor(s2[nt], off, 64);
            int   j2 = __shfl_xor(i2[nt], off, 64);
            top2_merge(s1[nt], i1[nt], s2[nt], i2[nt], t1, j1, t2, j2);
        }
    }

    if (lane < 16) {
#pragma unroll
        for (int nt = 0; nt < NT; ++nt) {
            int row = rowbase + nt * 16 + l16;
            uint2 p = {(unsigned int)i1[nt], (unsigned int)i2[nt]};
            *(uint2*)(cand + (size_t)row * 4 + half * 2) = p;
        }
    }
}

// ---------------------------------------------------------------------------
// Decide: exact fp32 rescore of 4 candidates; outputs z_q/idx/loss/cnt/fidx.
// 2 threads per row. Grid 512 x 256.
// ---------------------------------------------------------------------------
__global__ __launch_bounds__(256) void vq_decide(
    const float* __restrict__ z, const float* __restrict__ emb,
    const float* __restrict__ enorm, const unsigned int* __restrict__ cand,
    float* __restrict__ out_zq, float* __restrict__ out_idx,
    int* __restrict__ cnt, unsigned int* __restrict__ fidx,
    float* __restrict__ loss_acc)
{
    const int tid  = threadIdx.x;
    const int half = tid & 1;
    const int row  = blockIdx.x * 128 + (tid >> 1);

    float4 zr[16];
    const float4* zp = (const float4*)(z + (size_t)row * D_DIM + half * 64);
#pragma unroll
    for (int i = 0; i < 16; ++i) zr[i] = zp[i];

    uint4 cd = *(const uint4*)(cand + (size_t)row * 4);
    int j[4] = {(int)cd.x, (int)cd.y, (int)cd.z, (int)cd.w};

    float bs = 3.4e38f;
    int   bi = 0x7fffffff;
#pragma unroll
    for (int cidx = 0; cidx < 4; ++cidx) {
        int jj = j[cidx];
        const float4* ep = (const float4*)(emb + (size_t)jj * D_DIM + half * 64);
        float p = 0.f;
#pragma unroll
        for (int i = 0; i < 16; ++i) {
            float4 a = ep[i], zv = zr[i];
            p += zv.x * a.x + zv.y * a.y + zv.z * a.z + zv.w * a.w;
        }
        float d = p + __shfl_xor(p, 1, 64);
        float s = enorm[jj] - 2.0f * d;
        if (s < bs || (s == bs && jj < bi)) { bs = s; bi = jj; }
    }
    int best = bi;

    if (half == 0) {
        out_idx[row] = (float)best;
        fidx[row] = (unsigned int)best;
        atomicAdd(cnt + best, 1);
    }

    const float4* eq = (const float4*)(emb + (size_t)best * D_DIM + half * 64);
    float4* oz = (float4*)(out_zq + (size_t)row * D_DIM + half * 64);

    float ls = 0.f;
#pragma unroll
    for (int i = 0; i < 16; ++i) {
        float4 q = eq[i], zv = zr[i];
        float4 df = {q.x - zv.x, q.y - zv.y, q.z - zv.z, q.w - zv.w};
        ls += df.x * df.x + df.y * df.y + df.z * df.z + df.w * df.w;
        float4 o = {zv.x + df.x, zv.y + df.y, zv.z + df.z, zv.w + df.w};
        oz[i] = o;
    }

#pragma unroll
    for (int off = 32; off > 0; off >>= 1) ls += __shfl_down(ls, off, 64);
    if ((tid & 63) == 0) atomicAdd(loss_acc, ls);
}

// ---------------------------------------------------------------------------
// Mid: scan cnt -> cursor, ncs/smoothed/loss outputs. 1 block, 1024 thr.
// ---------------------------------------------------------------------------
__global__ void vq_mid(const float* __restrict__ cs, const int* __restrict__ cnt,
                       const float* __restrict__ loss_acc,
                       float* __restrict__ out_ncs, float* __restrict__ out_loss,
                       float* __restrict__ smoothed, int* __restrict__ cursor)
{
    __shared__ int tmp[K_CODES];
    __shared__ float red[K_CODES];
    int k = threadIdx.x;
    int c = cnt[k];
    tmp[k] = c;
    float ncs = cs[k] * DECAY_F + OMD_F * (float)c;
    out_ncs[k] = ncs;
    red[k] = ncs;
    __syncthreads();
    for (int off = 1; off < K_CODES; off <<= 1) {
        int t = (k >= off) ? tmp[k - off] : 0;
        __syncthreads();
        tmp[k] += t;
        __syncthreads();
    }
    cursor[k] = tmp[k] - c;
    for (int s = 512; s > 0; s >>= 1) {
        if (k < s) red[k] += red[k + s];
        __syncthreads();
    }
    float n = red[0];
    smoothed[k] = (ncs + EPS_F) / (n + (float)K_CODES * EPS_F) * n;
    if (k == 0) out_loss[0] = loss_acc[0] / (float)((size_t)N_ROWS * D_DIM);
}

__global__ void vq_scatter(const unsigned int* __restrict__ fidx,
                           int* __restrict__ cursor, unsigned int* __restrict__ bucket,
                           int* __restrict__ scode)
{
    int row = blockIdx.x * blockDim.x + threadIdx.x;
    int k = (int)fidx[row];
    int slot = atomicAdd(cursor + k, 1);
    bucket[slot] = (unsigned int)row;
    scode[slot]  = k;
}

// ---------------------------------------------------------------------------
// Skew-oblivious segment sum over code-sorted slots (R4-proven).
// ---------------------------------------------------------------------------
__global__ __launch_bounds__(128) void vq_segsum(
    const float* __restrict__ z, const unsigned int* __restrict__ bucket,
    const int* __restrict__ scode, float* __restrict__ be)
{
    __shared__ int sb[SEG_TILE];
    __shared__ int sc[SEG_TILE];
    const int tid = threadIdx.x;
    const int t0  = blockIdx.x * SEG_TILE;

    if (tid < SEG_TILE) sb[tid] = (int)bucket[t0 + tid];
    else if (tid < 2 * SEG_TILE) sc[tid - SEG_TILE] = scode[t0 + tid - SEG_TILE];
    __syncthreads();

    const int d = tid;
    float acc = 0.f;
    int cur = sc[0];

    for (int i = 0; i < SEG_TILE; i += 8) {
        float v[8];
#pragma unroll
        for (int jx = 0; jx < 8; ++jx)
            v[jx] = z[(size_t)sb[i + jx] * D_DIM + d];
#pragma unroll
        for (int jx = 0; jx < 8; ++jx) {
            int c = sc[i + jx];
            if (c != cur) {
                atomicAdd(be + (size_t)cur * D_DIM + d, acc);
                acc = 0.f;
                cur = c;
            }
            acc += v[jx];
        }
    }
    atomicAdd(be + (size_t)cur * D_DIM + d, acc);
}

__global__ void vq_fin2(const float* __restrict__ ema_w, const float* __restrict__ be,
                        const float* __restrict__ smoothed,
                        float* __restrict__ out_emb, float* __restrict__ out_ema)
{
    int i = blockIdx.x * blockDim.x + threadIdx.x;
    float e = ema_w[i] * DECAY_F + OMD_F * be[i];
    out_ema[i] = e;
    out_emb[i] = e / smoothed[i >> 7];
}

// ---------------------------------------------------------------------------
extern "C" void kernel_launch(void* const* d_in, const int* in_sizes, int n_in,
                              void* d_out, int out_size, void* d_ws, size_t ws_size,
                              hipStream_t stream) {
    const float* z   = (const float*)d_in[0];
    const float* emb = (const float*)d_in[1];
    const float* cs  = (const float*)d_in[2];
    const float* ema = (const float*)d_in[3];

    float* out    = (float*)d_out;
    float* o_zq   = out;
    float* o_idx  = o_zq + (size_t)N_ROWS * D_DIM;
    float* o_loss = o_idx + N_ROWS;
    float* o_emb  = o_loss + 1;
    float* o_ncs  = o_emb + K_CODES * D_DIM;
    float* o_ema  = o_ncs + K_CODES;

    float* ws = (float*)d_ws;
    int*            cnt      = (int*)(ws + WS_CNT);
    float*          lacc     = ws + WS_LOSS;
    float*          be       = ws + WS_BE;
    float*          enorm    = ws + WS_ENORM;
    float*          smoothed = ws + WS_SMOOTH;
    int*            cursor   = (int*)(ws + WS_CUR);
    unsigned int*   fidx     = (unsigned int*)(ws + WS_FIDX);
    unsigned int*   bucket   = (unsigned int*)(ws + WS_BUCKET);
    int*            scode    = (int*)(ws + WS_SCODE);
    unsigned int*   cand     = (unsigned int*)(ws + WS_CAND);
    unsigned short* eimg     = (unsigned short*)(ws + WS_EIMG);

    vq_prep<<<128, 256, 0, stream>>>(emb, ws, enorm, eimg);
    vq_score<<<512, 256, 0, stream>>>(z, eimg, enorm, cand);
    vq_decide<<<512, 256, 0, stream>>>(z, emb, enorm, cand,
                                       o_zq, o_idx, cnt, fidx, lacc);
    vq_mid<<<1, K_CODES, 0, stream>>>(cs, cnt, lacc, o_ncs, o_loss, smoothed, cursor);
    vq_scatter<<<N_ROWS / 256, 256, 0, stream>>>(fidx, cursor, bucket, scode);
    vq_segsum<<<N_ROWS / SEG_TILE, 128, 0, stream>>>(z, bucket, scode, be);
    vq_fin2<<<K_CODES * D_DIM / 256, 256, 0, stream>>>(ema, be, smoothed, o_emb, o_ema);
}